// Round 1
// baseline (574.603 us; speedup 1.0000x reference)
//
#include <hip/hip_runtime.h>

// metaCLF: per-voxel MLP filter generation + filtering.
// x: [2,32,96^3] f32, d_all: [2,6,96^3] f32
// W1:[16,2] W2:[3,16] G1:[32,27] G2:[64,32] G3:[32,64]
// out: [2,1,96^3] f32
//
// Round 1: scalar fp32, one thread per voxel. Weights indexed uniformly
// (compile-time constants after unroll) -> compiler emits s_load; each FMA is
// v_fmac_f32 with an SGPR operand. G3 fused with the final x-dot to cap
// live registers at h2[64] + ~temps.

constexpr int V3   = 96 * 96 * 96;   // 884736
constexpr int NVOX = 2 * V3;         // 1769472

__global__ __launch_bounds__(256) void metaclf_fused(
    const float* __restrict__ x,
    const float* __restrict__ d_all,
    const float* __restrict__ W1,
    const float* __restrict__ W2,
    const float* __restrict__ G1,
    const float* __restrict__ G2,
    const float* __restrict__ G3,
    float* __restrict__ out)
{
    const int idx = blockIdx.x * 256 + threadIdx.x;
    if (idx >= NVOX) return;
    const int b = (idx >= V3) ? 1 : 0;   // B=2: avoid integer divide
    const int v = idx - b * V3;

    // ---- encode: 2 -> 16 (relu) -> 3, for each of the 3 axes ----
    float e[3][3];
#pragma unroll
    for (int a = 0; a < 3; ++a) {
        const float d0 = d_all[(b * 6 + 2 * a    ) * V3 + v];
        const float d1 = d_all[(b * 6 + 2 * a + 1) * V3 + v];
        float a0 = 0.f, a1 = 0.f, a2 = 0.f;
#pragma unroll
        for (int k = 0; k < 16; ++k) {
            const float t = fmaxf(fmaf(W1[k * 2], d0, W1[k * 2 + 1] * d1), 0.f);
            a0 = fmaf(W2[0 * 16 + k], t, a0);
            a1 = fmaf(W2[1 * 16 + k], t, a1);
            a2 = fmaf(W2[2 * 16 + k], t, a2);
        }
        e[a][0] = a0; e[a][1] = a1; e[a][2] = a2;
    }

    // ---- kron(kron(x_x,y_y),z_z): enced[i*9 + j*3 + k] = ex[i]*ey[j]*ez[k] ----
    float enced[27];
#pragma unroll
    for (int i = 0; i < 3; ++i)
#pragma unroll
        for (int j = 0; j < 3; ++j) {
            const float p = e[0][i] * e[1][j];
#pragma unroll
            for (int k = 0; k < 3; ++k)
                enced[i * 9 + j * 3 + k] = p * e[2][k];
        }

    // ---- G1: 27 -> 32, relu ----
    float h1[32];
#pragma unroll
    for (int o = 0; o < 32; ++o) {
        float s = 0.f;
#pragma unroll
        for (int m = 0; m < 27; ++m) s = fmaf(G1[o * 27 + m], enced[m], s);
        h1[o] = fmaxf(s, 0.f);
    }

    // ---- G2: 32 -> 64, relu ----
    float h2[64];
#pragma unroll
    for (int p = 0; p < 64; ++p) {
        float s = 0.f;
#pragma unroll
        for (int o = 0; o < 32; ++o) s = fmaf(G2[p * 32 + o], h1[o], s);
        h2[p] = fmaxf(s, 0.f);
    }

    // ---- G3: 64 -> 32 (filters), fused with out = sum_c x[c] * f[c] ----
    float result = 0.f;
#pragma unroll
    for (int c = 0; c < 32; ++c) {
        float s = 0.f;
#pragma unroll
        for (int p = 0; p < 64; ++p) s = fmaf(G3[c * 64 + p], h2[p], s);
        result = fmaf(x[(b * 32 + c) * V3 + v], s, result);
    }

    out[b * V3 + v] = result;
}

extern "C" void kernel_launch(void* const* d_in, const int* in_sizes, int n_in,
                              void* d_out, int out_size, void* d_ws, size_t ws_size,
                              hipStream_t stream) {
    const float* x     = (const float*)d_in[0];
    const float* d_all = (const float*)d_in[1];
    const float* W1    = (const float*)d_in[2];
    const float* W2    = (const float*)d_in[3];
    const float* G1    = (const float*)d_in[4];
    const float* G2    = (const float*)d_in[5];
    const float* G3    = (const float*)d_in[6];
    float* out = (float*)d_out;

    const int threads = 256;
    const int blocks  = (NVOX + threads - 1) / threads;
    metaclf_fused<<<blocks, threads, 0, stream>>>(x, d_all, W1, W2, G1, G2, G3, out);
}